// Round 1
// baseline (199.710 us; speedup 1.0000x reference)
//
#include <hip/hip_runtime.h>
#include <cstdint>

// RNN: B=8192, T=2048, I=1, H=2, O=1.
// One thread per batch element; sequential scan over its (length-limited) row.
// Latency-bound: 8192 threads = 128 waves only. Critical path = per-step
// fma,fma,exp2,add,rcp,fma chain; memory prefetched 32 steps ahead via a
// rolling 8x float4 register buffer.

#define T_LEN 2048

__device__ __forceinline__ float fast_exp2(float x) {
#if __has_builtin(__builtin_amdgcn_exp2f)
  return __builtin_amdgcn_exp2f(x);
#else
  return exp2f(x);
#endif
}

__device__ __forceinline__ float fast_rcp(float x) {
#if __has_builtin(__builtin_amdgcn_rcpf)
  return __builtin_amdgcn_rcpf(x);
#else
  return 1.0f / x;
#endif
}

// One RNN step. All coefficients pre-scaled by S = 2*log2(e), so
// tanh(z) = 1 - 2/(exp2(S*z) + 1) needs no extra multiply on the chain.
__device__ __forceinline__ void rnn_step(float xv,
                                         float sw0, float sw1,
                                         float sc0, float sc1,
                                         float A00, float A01,
                                         float A10, float A11,
                                         float& h0, float& h1) {
  // off-critical-path (depends only on xv):
  float sg0 = fmaf(sw0, xv, sc0);
  float sg1 = fmaf(sw1, xv, sc1);
  // critical path:
  float z0 = fmaf(A00, h0, fmaf(A01, h1, sg0));
  float z1 = fmaf(A10, h0, fmaf(A11, h1, sg1));
  float e0 = fast_exp2(z0);
  float e1 = fast_exp2(z1);
  float r0 = fast_rcp(e0 + 1.0f);
  float r1 = fast_rcp(e1 + 1.0f);
  h0 = fmaf(-2.0f, r0, 1.0f);
  h1 = fmaf(-2.0f, r1, 1.0f);
}

__global__ __launch_bounds__(64) void rnn_scan(
    const float* __restrict__ x, const int* __restrict__ lengths,
    const float* __restrict__ wih, const float* __restrict__ whh,
    const float* __restrict__ bih, const float* __restrict__ bhh,
    const float* __restrict__ fcw, const float* __restrict__ fcb,
    float* __restrict__ out) {
  const int b = blockIdx.x * 64 + threadIdx.x;

  const float S = 2.885390081777926f;  // 2*log2(e)
  const float sw0 = S * wih[0];
  const float sw1 = S * wih[1];
  const float sc0 = S * (bih[0] + bhh[0]);
  const float sc1 = S * (bih[1] + bhh[1]);
  const float A00 = S * whh[0];
  const float A01 = S * whh[1];
  const float A10 = S * whh[2];
  const float A11 = S * whh[3];

  const int len = lengths[b];  // in [1, 2047]
  const float* __restrict__ xp = x + (size_t)b * T_LEN;
  const float4* __restrict__ xp4 = (const float4*)xp;

  float h0 = 0.0f, h1 = 0.0f;

  // Main loop: groups of 32 steps (8 float4). Prefetch next group's 8 loads
  // before running the 32-step dependent chain (~900 cyc of compute covers
  // HBM latency). All clamped loads stay inside this row (indices <= 511).
  const int ngroups = len >> 5;
  if (ngroups > 0) {
    float4 cur[8], nxt[8];
#pragma unroll
    for (int i = 0; i < 8; ++i) cur[i] = xp4[i];
    for (int g = 0; g < ngroups; ++g) {
      const int nb = min((g + 1) * 8, 504);  // 504+7 = 511 max float4 index
#pragma unroll
      for (int i = 0; i < 8; ++i) nxt[i] = xp4[nb + i];
#pragma unroll
      for (int i = 0; i < 8; ++i) {
        rnn_step(cur[i].x, sw0, sw1, sc0, sc1, A00, A01, A10, A11, h0, h1);
        rnn_step(cur[i].y, sw0, sw1, sc0, sc1, A00, A01, A10, A11, h0, h1);
        rnn_step(cur[i].z, sw0, sw1, sc0, sc1, A00, A01, A10, A11, h0, h1);
        rnn_step(cur[i].w, sw0, sw1, sc0, sc1, A00, A01, A10, A11, h0, h1);
      }
#pragma unroll
      for (int i = 0; i < 8; ++i) cur[i] = nxt[i];
    }
  }
  // Tail: remaining len & 31 steps, scalar loads (in-row: t < len <= 2047).
  for (int t = ngroups << 5; t < len; ++t) {
    rnn_step(xp[t], sw0, sw1, sc0, sc1, A00, A01, A10, A11, h0, h1);
  }

  out[b] = fmaf(h0, fcw[0], fmaf(h1, fcw[1], fcb[0]));
}

extern "C" void kernel_launch(void* const* d_in, const int* in_sizes, int n_in,
                              void* d_out, int out_size, void* d_ws,
                              size_t ws_size, hipStream_t stream) {
  const float* x = (const float*)d_in[0];
  const int* lengths = (const int*)d_in[1];
  const float* wih = (const float*)d_in[2];
  const float* whh = (const float*)d_in[3];
  const float* bih = (const float*)d_in[4];
  const float* bhh = (const float*)d_in[5];
  const float* fcw = (const float*)d_in[6];
  const float* fcb = (const float*)d_in[7];
  float* out = (float*)d_out;

  const int B = 8192;
  rnn_scan<<<B / 64, 64, 0, stream>>>(x, lengths, wih, whh, bih, bhh, fcw,
                                      fcb, out);
}

// Round 2
// 105.918 us; speedup vs baseline: 1.8855x; 1.8855x over previous
//
#include <hip/hip_runtime.h>
#include <cstdint>

// RNN: B=8192, T=2048, I=1, H=2, O=1. One thread per batch element.
//
// R2: truncated fading-memory scan. h_{t+1}=tanh(W_hh h_t + c(x_t)) is a
// contraction with factor sigma = sigma_max(W_hh) (tanh is 1-Lipschitz).
// Output error from starting at t = len-K with h=0 is <= ~1.5*sigma^K.
// Pick K s.t. sigma^K <= 7e-6 (870x under the 8.75e-3 threshold).
// K is computed at runtime from W_hh (wave-uniform). If sigma too close to
// 1 (K > 256), fall back to the full scan (R1 baseline, known-correct).
//
// Short sequences (len < K'): steps with t<0 are masked by forcing the
// input term sg to 0 OFF the critical path; with h starting at 0,
// z = A*0 + 0 = 0 and tanh(0) = 0 exactly (exp2(0)=1, rcp(2)=0.5 exact),
// so h stays 0 through the masked prefix with no cndmask on the chain.

#define T_LEN 2048

__device__ __forceinline__ float fast_exp2(float x) {
#if __has_builtin(__builtin_amdgcn_exp2f)
  return __builtin_amdgcn_exp2f(x);
#else
  return exp2f(x);
#endif
}

__device__ __forceinline__ float fast_rcp(float x) {
#if __has_builtin(__builtin_amdgcn_rcpf)
  return __builtin_amdgcn_rcpf(x);
#else
  return 1.0f / x;
#endif
}

// One RNN step. Coefficients pre-scaled by S = 2*log2(e):
// tanh(z) = 1 - 2/(exp2(S*z)+1).
__device__ __forceinline__ void rnn_step(float sg0, float sg1,
                                         float A00, float A01,
                                         float A10, float A11,
                                         float& h0, float& h1) {
  float z0 = fmaf(A00, h0, fmaf(A01, h1, sg0));
  float z1 = fmaf(A10, h0, fmaf(A11, h1, sg1));
  float e0 = fast_exp2(z0);
  float e1 = fast_exp2(z1);
  float r0 = fast_rcp(e0 + 1.0f);
  float r1 = fast_rcp(e1 + 1.0f);
  h0 = fmaf(-2.0f, r0, 1.0f);
  h1 = fmaf(-2.0f, r1, 1.0f);
}

__global__ __launch_bounds__(64) void rnn_scan(
    const float* __restrict__ x, const int* __restrict__ lengths,
    const float* __restrict__ wih, const float* __restrict__ whh,
    const float* __restrict__ bih, const float* __restrict__ bhh,
    const float* __restrict__ fcw, const float* __restrict__ fcb,
    float* __restrict__ out) {
  const int b = blockIdx.x * 64 + threadIdx.x;

  const float S = 2.885390081777926f;  // 2*log2(e)
  const float wa = whh[0], wb = whh[1], wc = whh[2], wd = whh[3];
  const float sw0 = S * wih[0];
  const float sw1 = S * wih[1];
  const float sc0 = S * (bih[0] + bhh[0]);
  const float sc1 = S * (bih[1] + bhh[1]);
  const float A00 = S * wa, A01 = S * wb;
  const float A10 = S * wc, A11 = S * wd;

  // sigma_max of 2x2 W_hh (exact closed form), slightly inflated for fp.
  const float g11 = wa * wa + wc * wc;
  const float g22 = wb * wb + wd * wd;
  const float g12 = wa * wb + wc * wd;
  const float half_tr = 0.5f * (g11 + g22);
  const float half_df = 0.5f * (g11 - g22);
  const float s2 = half_tr + sqrtf(half_df * half_df + g12 * g12);
  const float sigma = sqrtf(s2) * 1.0002f;

  int K;
  if (sigma > 1e-4f && sigma < 0.999f) {
    // sigma^K <= 7e-6  ->  K = ceil(ln(7e-6)/ln(sigma)); ln(7e-6) = -11.8696
    K = (int)ceilf(-11.8696f / logf(sigma));
    if (K < 8) K = 8;
  } else if (!(sigma > 1e-4f)) {
    K = 8;  // sigma ~ 0 (or NaN handled below)
  } else {
    K = 1 << 20;  // too close to 1: force fallback
  }
  if (!(sigma == sigma)) K = 1 << 20;  // NaN guard -> fallback

  const int len = lengths[b];  // in [1, 2047]
  const float* __restrict__ xp = x + (size_t)b * T_LEN;

  float h0 = 0.0f, h1 = 0.0f;

  if (K <= 256) {
    // ---- fast path: uniform K' steps, masked prefix ----
    const int Kp = (K + 15) & ~15;  // multiple of 16, <= 256
    const int t0 = len - Kp;        // may be negative

    float xs[16];
#pragma unroll
    for (int i = 0; i < 16; ++i) {
      const int t = t0 + i;
      xs[i] = xp[min(max(t, 0), T_LEN - 1)];
    }
    for (int blk = 0; blk < Kp; blk += 16) {
      float xn[16];
#pragma unroll
      for (int i = 0; i < 16; ++i) {
        const int t = t0 + blk + 16 + i;
        xn[i] = xp[min(max(t, 0), T_LEN - 1)];
      }
#pragma unroll
      for (int i = 0; i < 16; ++i) {
        const int t = t0 + blk + i;
        float sg0 = fmaf(sw0, xs[i], sc0);
        float sg1 = fmaf(sw1, xs[i], sc1);
        const bool v = t >= 0;
        sg0 = v ? sg0 : 0.0f;  // off-chain masking; keeps h == 0 in prefix
        sg1 = v ? sg1 : 0.0f;
        rnn_step(sg0, sg1, A00, A01, A10, A11, h0, h1);
      }
#pragma unroll
      for (int i = 0; i < 16; ++i) xs[i] = xn[i];
    }
  } else {
    // ---- fallback: full scan (R1 baseline, known-correct) ----
    const float4* __restrict__ xp4 = (const float4*)xp;
    const int ngroups = len >> 5;
    if (ngroups > 0) {
      float4 cur[8], nxt[8];
#pragma unroll
      for (int i = 0; i < 8; ++i) cur[i] = xp4[i];
      for (int g = 0; g < ngroups; ++g) {
        const int nb = min((g + 1) * 8, 504);
#pragma unroll
        for (int i = 0; i < 8; ++i) nxt[i] = xp4[nb + i];
#pragma unroll
        for (int i = 0; i < 8; ++i) {
          rnn_step(fmaf(sw0, cur[i].x, sc0), fmaf(sw1, cur[i].x, sc1),
                   A00, A01, A10, A11, h0, h1);
          rnn_step(fmaf(sw0, cur[i].y, sc0), fmaf(sw1, cur[i].y, sc1),
                   A00, A01, A10, A11, h0, h1);
          rnn_step(fmaf(sw0, cur[i].z, sc0), fmaf(sw1, cur[i].z, sc1),
                   A00, A01, A10, A11, h0, h1);
          rnn_step(fmaf(sw0, cur[i].w, sc0), fmaf(sw1, cur[i].w, sc1),
                   A00, A01, A10, A11, h0, h1);
        }
#pragma unroll
        for (int i = 0; i < 8; ++i) cur[i] = nxt[i];
      }
    }
    for (int t = ngroups << 5; t < len; ++t) {
      rnn_step(fmaf(sw0, xp[t], sc0), fmaf(sw1, xp[t], sc1),
               A00, A01, A10, A11, h0, h1);
    }
  }

  out[b] = fmaf(h0, fcw[0], fmaf(h1, fcw[1], fcb[0]));
}

extern "C" void kernel_launch(void* const* d_in, const int* in_sizes, int n_in,
                              void* d_out, int out_size, void* d_ws,
                              size_t ws_size, hipStream_t stream) {
  const float* x = (const float*)d_in[0];
  const int* lengths = (const int*)d_in[1];
  const float* wih = (const float*)d_in[2];
  const float* whh = (const float*)d_in[3];
  const float* bih = (const float*)d_in[4];
  const float* bhh = (const float*)d_in[5];
  const float* fcw = (const float*)d_in[6];
  const float* fcb = (const float*)d_in[7];
  float* out = (float*)d_out;

  const int B = 8192;
  rnn_scan<<<B / 64, 64, 0, stream>>>(x, lengths, wih, whh, bih, bhh, fcw,
                                      fcb, out);
}

// Round 3
// 101.302 us; speedup vs baseline: 1.9714x; 1.0456x over previous
//
#include <hip/hip_runtime.h>
#include <cstdint>

// RNN: B=8192, T=2048, I=1, H=2, O=1. One thread per batch element.
//
// R3: (a) truncated fading-memory scan with relaxed target sigma^K <= 1e-3
// (rigorous worst-case output error <= sqrt(2)*sigma^K = 1.4e-3, 6x under
// the 8.75e-3 threshold); (b) 5-op dependent chain via r-state:
//   r = rcp(exp2(u) + 0.5),  h = 1 - r,  u = z - 1 (z = 2*log2e * prezact)
// so the next step's u' = sg' - A00*r0 - A01*r1 with all constants
// (S*(b_ih+b_hh) + S*W_hh.rowsum - 1) folded into sc. Chain per step:
// fma, fma, exp2, add, rcp  (was 6 ops with the h-state form).
//
// Masked prefix (t < 0 for lanes with len < Kp): force sg to the constant
// (A00+A01-1) off the critical path -> u = -1 -> exp2 = 0.5 -> d = 1.0
// -> r = 1.0 (all exact), i.e. h stays exactly 0. No cndmask on the chain.

#define T_LEN 2048

__device__ __forceinline__ float fast_exp2(float x) {
#if __has_builtin(__builtin_amdgcn_exp2f)
  return __builtin_amdgcn_exp2f(x);
#else
  return exp2f(x);
#endif
}

__device__ __forceinline__ float fast_rcp(float x) {
#if __has_builtin(__builtin_amdgcn_rcpf)
  return __builtin_amdgcn_rcpf(x);
#else
  return 1.0f / x;
#endif
}

// One step in r-state. sg already includes the +rowsum-1 constant fold.
__device__ __forceinline__ void rnn_step_r(float sg0, float sg1,
                                           float A00, float A01,
                                           float A10, float A11,
                                           float& r0, float& r1) {
  float u0 = fmaf(-A00, r0, fmaf(-A01, r1, sg0));
  float u1 = fmaf(-A10, r0, fmaf(-A11, r1, sg1));
  float e0 = fast_exp2(u0);
  float e1 = fast_exp2(u1);
  r0 = fast_rcp(e0 + 0.5f);
  r1 = fast_rcp(e1 + 0.5f);
}

__global__ __launch_bounds__(64) void rnn_scan(
    const float* __restrict__ x, const int* __restrict__ lengths,
    const float* __restrict__ wih, const float* __restrict__ whh,
    const float* __restrict__ bih, const float* __restrict__ bhh,
    const float* __restrict__ fcw, const float* __restrict__ fcb,
    float* __restrict__ out) {
  const int b = blockIdx.x * 64 + threadIdx.x;

  const float S = 2.885390081777926f;  // 2*log2(e)
  const float wa = whh[0], wb = whh[1], wc = whh[2], wd = whh[3];
  const float A00 = S * wa, A01 = S * wb;
  const float A10 = S * wc, A11 = S * wd;
  const float sw0 = S * wih[0];
  const float sw1 = S * wih[1];
  // sc folds: S*(b_ih + b_hh) + rowsum(A) - 1
  const float sc0 = fmaf(S, bih[0] + bhh[0], A00 + A01 - 1.0f);
  const float sc1 = fmaf(S, bih[1] + bhh[1], A10 + A11 - 1.0f);
  const float m0 = A00 + A01 - 1.0f;  // masked-step sg constant -> u = -1
  const float m1 = A10 + A11 - 1.0f;

  // sigma_max of 2x2 W_hh (exact closed form), slightly inflated for fp.
  const float g11 = wa * wa + wc * wc;
  const float g22 = wb * wb + wd * wd;
  const float g12 = wa * wb + wc * wd;
  const float half_tr = 0.5f * (g11 + g22);
  const float half_df = 0.5f * (g11 - g22);
  const float s2 = half_tr + sqrtf(half_df * half_df + g12 * g12);
  const float sigma = sqrtf(s2) * 1.0002f;

  int K;
  if (sigma > 1e-4f && sigma < 0.999f) {
    // sigma^K <= 1e-3  ->  K = ceil(ln(1e-3)/ln(sigma)); ln(1e-3) = -6.9078
    K = (int)ceilf(-6.9078f / logf(sigma));
    if (K < 8) K = 8;
  } else if (!(sigma > 1e-4f)) {
    K = 8;  // sigma ~ 0
  } else {
    K = 1 << 20;  // too close to 1: force full-scan fallback
  }
  if (!(sigma == sigma)) K = 1 << 20;  // NaN guard

  const int len = lengths[b];  // in [1, 2047]
  const float* __restrict__ xp = x + (size_t)b * T_LEN;

  float r0 = 1.0f, r1 = 1.0f;  // h = 0

  if (K <= 256) {
    // ---- fast path: uniform Kp steps, masked prefix ----
    const int Kp = (K + 15) & ~15;  // multiple of 16, <= 256
    const int t0 = len - Kp;        // may be negative

    float xs[16];
#pragma unroll
    for (int i = 0; i < 16; ++i) {
      const int t = t0 + i;
      xs[i] = xp[min(max(t, 0), T_LEN - 1)];
    }
    for (int blk = 0; blk < Kp; blk += 16) {
      float xn[16];
#pragma unroll
      for (int i = 0; i < 16; ++i) {
        const int t = t0 + blk + 16 + i;
        xn[i] = xp[min(max(t, 0), T_LEN - 1)];
      }
#pragma unroll
      for (int i = 0; i < 16; ++i) {
        const int t = t0 + blk + i;
        const bool v = t >= 0;
        const float sg0 = v ? fmaf(sw0, xs[i], sc0) : m0;  // off-chain mask
        const float sg1 = v ? fmaf(sw1, xs[i], sc1) : m1;
        rnn_step_r(sg0, sg1, A00, A01, A10, A11, r0, r1);
      }
#pragma unroll
      for (int i = 0; i < 16; ++i) xs[i] = xn[i];
    }
  } else {
    // ---- fallback: full exact scan (r-state form) ----
    const float4* __restrict__ xp4 = (const float4*)xp;
    const int ngroups = len >> 5;
    if (ngroups > 0) {
      float4 cur[8], nxt[8];
#pragma unroll
      for (int i = 0; i < 8; ++i) cur[i] = xp4[i];
      for (int g = 0; g < ngroups; ++g) {
        const int nb = min((g + 1) * 8, 504);
#pragma unroll
        for (int i = 0; i < 8; ++i) nxt[i] = xp4[nb + i];
#pragma unroll
        for (int i = 0; i < 8; ++i) {
          rnn_step_r(fmaf(sw0, cur[i].x, sc0), fmaf(sw1, cur[i].x, sc1),
                     A00, A01, A10, A11, r0, r1);
          rnn_step_r(fmaf(sw0, cur[i].y, sc0), fmaf(sw1, cur[i].y, sc1),
                     A00, A01, A10, A11, r0, r1);
          rnn_step_r(fmaf(sw0, cur[i].z, sc0), fmaf(sw1, cur[i].z, sc1),
                     A00, A01, A10, A11, r0, r1);
          rnn_step_r(fmaf(sw0, cur[i].w, sc0), fmaf(sw1, cur[i].w, sc1),
                     A00, A01, A10, A11, r0, r1);
        }
#pragma unroll
        for (int i = 0; i < 8; ++i) cur[i] = nxt[i];
      }
    }
    for (int t = ngroups << 5; t < len; ++t) {
      rnn_step_r(fmaf(sw0, xp[t], sc0), fmaf(sw1, xp[t], sc1),
                 A00, A01, A10, A11, r0, r1);
    }
  }

  // out = fc.(1 - r) + fcb = (fc0 + fc1 + fcb) - fc0*r0 - fc1*r1
  const float fc0 = fcw[0], fc1 = fcw[1];
  const float csum = fc0 + fc1 + fcb[0];
  out[b] = fmaf(-fc0, r0, fmaf(-fc1, r1, csum));
}

extern "C" void kernel_launch(void* const* d_in, const int* in_sizes, int n_in,
                              void* d_out, int out_size, void* d_ws,
                              size_t ws_size, hipStream_t stream) {
  const float* x = (const float*)d_in[0];
  const int* lengths = (const int*)d_in[1];
  const float* wih = (const float*)d_in[2];
  const float* whh = (const float*)d_in[3];
  const float* bih = (const float*)d_in[4];
  const float* bhh = (const float*)d_in[5];
  const float* fcw = (const float*)d_in[6];
  const float* fcb = (const float*)d_in[7];
  float* out = (float*)d_out;

  const int B = 8192;
  rnn_scan<<<B / 64, 64, 0, stream>>>(x, lengths, wih, whh, bih, bhh, fcw,
                                      fcb, out);
}